// Round 2
// baseline (136.607 us; speedup 1.0000x reference)
//
#include <hip/hip_runtime.h>
#include <hip/hip_bf16.h>
#include <math.h>

#define BATCH   2048
#define NINTRS  256
#define VALID   128
#define NATOMS  256
#define DDIM    28   // 3*9+1

typedef float  f32x4  __attribute__((ext_vector_type(4)));
typedef short  bf16x8 __attribute__((ext_vector_type(8)));

__device__ __forceinline__ unsigned short f32_to_bf16(float f) {
    unsigned int u = __float_as_uint(f);
    u = (u + 0x7FFFu + ((u >> 16) & 1u)) >> 16;   // RNE
    return (unsigned short)u;
}

// One block per ray. Fuses: SH-contracted atom dictionary (phase B, LDS),
// trilinear weights (phase A), per-ray MFMA GEMM (phase C, software-pipelined
// q prefetch), weight+reduce epilogue, transmittance render scan (wave 0).
__global__ __launch_bounds__(256, 4)   // VGPR cap 128: room for q-load pipeline
void shdict_fused(const float* __restrict__ q,      // [BATCH*VALID][256]
                  const float* __restrict__ atoms,  // [256][28][8]
                  const float* __restrict__ ipts,   // [BATCH*VALID][3]
                  const float* __restrict__ intr,   // [BATCH][257]
                  const float* __restrict__ raysd,  // [BATCH][3]
                  float* __restrict__ out_rgb,      // [BATCH][3]
                  float* __restrict__ out_alpha,    // [BATCH][256]
                  float* __restrict__ out_depth)    // [BATCH]
{
    __shared__ char  bs[32 * 256 * 2];      // Bs[col][a] bf16, XOR-swizzled
    __shared__ float w_lds[VALID][9];       // +1 pad: conflict-free epilogue
    __shared__ float pr_lds[VALID][5];      // +1 pad: conflict-free scan

    const int ray  = blockIdx.x;
    const int tid  = threadIdx.x;
    const int lane = tid & 63;
    const int wav  = tid >> 6;

    // ---- Issue q prefetch for ks=0,1 FIRST (HBM ~900cy; the phase-B
    // barrier's vmcnt(0) drain guarantees arrival before phase C). ----
    const int row  = lane & 15;   // A row / B col within tile
    const int kgrp = lane >> 4;   // k sub-group of 8 within K=32
    const float* qb0 = q + (size_t)(ray*VALID + wav*32 + row) * NATOMS + kgrp*8;
    const float* qb1 = qb0 + 16 * NATOMS;

    f32x4 pv[2][4];
    #pragma unroll
    for (int s = 0; s < 2; ++s) {
        const float* p0 = qb0 + s*32;
        const float* p1 = qb1 + s*32;
        pv[s][0] = *(const f32x4*)(p0);
        pv[s][1] = *(const f32x4*)(p0 + 4);
        pv[s][2] = *(const f32x4*)(p1);
        pv[s][3] = *(const f32x4*)(p1 + 4);
    }

    // ---- SH basis for this ray (redundant per thread) ----
    const float rdx = raysd[ray*3+0], rdy = raysd[ray*3+1], rdz = raysd[ray*3+2];
    const float ss  = rdx*rdx + rdy*rdy + rdz*rdz;
    const float rn  = rsqrtf(ss);
    const float x = rdx*rn, y = rdy*rn, z = rdz*rn;
    float sh[9];
    sh[0] = 0.28209479177387814f;
    sh[1] = -0.4886025119029199f * y;
    sh[2] =  0.4886025119029199f * z;
    sh[3] = -0.4886025119029199f * x;
    sh[4] =  1.0925484305920792f * x * y;
    sh[5] = -1.0925484305920792f * y * z;
    sh[6] =  0.31539156525252005f * (2.0f*z*z - x*x - y*y);
    sh[7] = -1.0925484305920792f * x * z;
    sh[8] =  0.5462742152960396f * (x*x - y*y);

    // ---- Phase A: trilinear weights for the 128 valid points ----
    if (tid < VALID) {
        const int n = ray * VALID + tid;
        const float px = ipts[n*3+0]*128.0f + 1e-5f;
        const float py = ipts[n*3+1]*128.0f + 1e-5f;
        const float pz = ipts[n*3+2]*128.0f + 1e-5f;
        const float fx = px - floorf(px);
        const float fy = py - floorf(py);
        const float fz = pz - floorf(pz);
        #pragma unroll
        for (int c = 0; c < 8; ++c) {
            const float wx = (c & 4) ? fx : 1.0f - fx;
            const float wy = (c & 2) ? fy : 1.0f - fy;
            const float wz = (c & 1) ? fz : 1.0f - fz;
            w_lds[tid][c] = wx * wy * wz;
        }
    }

    // ---- Phase B: Bs[col][a], a == tid.  col = kp*8+c; kp<3 are
    // sh-contracted rgb rows, col 24..31 is the raw sigma row (d=27). ----
    {
        const int a = tid;
        const float* __restrict__ arow = atoms + (size_t)a * (DDIM*8);
        float acc[3][8];
        #pragma unroll
        for (int k = 0; k < 3; ++k)
            #pragma unroll
            for (int c = 0; c < 8; ++c) acc[k][c] = 0.0f;
        #pragma unroll
        for (int d = 0; d < 27; ++d) {
            const int kp = d / 9, j = d - kp*9;
            const float s = sh[j];
            f32x4 a0 = *(const f32x4*)(arow + d*8);
            f32x4 a1 = *(const f32x4*)(arow + d*8 + 4);
            #pragma unroll
            for (int c = 0; c < 4; ++c) {
                acc[kp][c]   = fmaf(s, a0[c], acc[kp][c]);
                acc[kp][c+4] = fmaf(s, a1[c], acc[kp][c+4]);
            }
        }
        #pragma unroll
        for (int kp = 0; kp < 3; ++kp)
            #pragma unroll
            for (int c = 0; c < 8; ++c) {
                const int col = kp*8 + c;
                unsigned byte = ((unsigned)col << 9) + ((unsigned)a << 1);
                byte ^= (unsigned)((col & 7) << 4);
                *(unsigned short*)(bs + byte) = f32_to_bf16(acc[kp][c]);
            }
        f32x4 s0 = *(const f32x4*)(arow + 27*8);
        f32x4 s1 = *(const f32x4*)(arow + 27*8 + 4);
        #pragma unroll
        for (int c = 0; c < 8; ++c) {
            const int col = 24 + c;
            unsigned byte = ((unsigned)col << 9) + ((unsigned)a << 1);
            byte ^= (unsigned)((col & 7) << 4);
            *(unsigned short*)(bs + byte) = f32_to_bf16(c < 4 ? s0[c] : s1[c-4]);
        }
    }
    __syncthreads();   // drains vmcnt: pv[0..1] have landed too

    // ---- Phase C: C[pt, col] = sum_a q[pt,a] * Bs[col, a] via MFMA,
    // software-pipelined at distance 2. ----
    f32x4 acc[2][2];
    #pragma unroll
    for (int m = 0; m < 2; ++m)
        #pragma unroll
        for (int n = 0; n < 2; ++n)
            acc[m][n] = (f32x4){0.f, 0.f, 0.f, 0.f};

    #pragma unroll
    for (int ks = 0; ks < 8; ++ks) {
        const int b = ks & 1;
        // consume pv[b] -> bf16 A-fragments
        bf16x8 af[2];
        #pragma unroll
        for (int j = 0; j < 4; ++j) {
            af[0][j]   = (short)f32_to_bf16(pv[b][0][j]);
            af[0][j+4] = (short)f32_to_bf16(pv[b][1][j]);
            af[1][j]   = (short)f32_to_bf16(pv[b][2][j]);
            af[1][j+4] = (short)f32_to_bf16(pv[b][3][j]);
        }
        // reissue pv[b] for ks+2 (overlaps with MFMA below)
        if (ks + 2 < 8) {
            const float* p0 = qb0 + (ks+2)*32;
            const float* p1 = qb1 + (ks+2)*32;
            pv[b][0] = *(const f32x4*)(p0);
            pv[b][1] = *(const f32x4*)(p0 + 4);
            pv[b][2] = *(const f32x4*)(p1);
            pv[b][3] = *(const f32x4*)(p1 + 4);
        }
        bf16x8 bfrag[2];
        const int abase = ks*32 + kgrp*8;
        #pragma unroll
        for (int nt = 0; nt < 2; ++nt) {
            const int col = nt*16 + row;
            unsigned byte = ((unsigned)col << 9) + ((unsigned)abase << 1);
            byte ^= (unsigned)((col & 7) << 4);
            bfrag[nt] = *(const bf16x8*)(bs + byte);
        }
        acc[0][0] = __builtin_amdgcn_mfma_f32_16x16x32_bf16(af[0], bfrag[0], acc[0][0], 0, 0, 0);
        acc[0][1] = __builtin_amdgcn_mfma_f32_16x16x32_bf16(af[0], bfrag[1], acc[0][1], 0, 0, 0);
        acc[1][0] = __builtin_amdgcn_mfma_f32_16x16x32_bf16(af[1], bfrag[0], acc[1][0], 0, 0, 0);
        acc[1][1] = __builtin_amdgcn_mfma_f32_16x16x32_bf16(af[1], bfrag[1], acc[1][1], 0, 0, 0);
    }

    // ---- Epilogue: out[pt,kp] = sum_c w[pt,c] * C[pt, kp*8+c] ----
    // D layout: lane holds D[(lane>>4)*4 + r][lane&15].
    const int cc  = lane & 7;
    const int kph = (lane & 15) >> 3;
    #pragma unroll
    for (int m = 0; m < 2; ++m) {
        const int ptb = wav*32 + m*16 + kgrp*4;
        #pragma unroll
        for (int nt = 0; nt < 2; ++nt) {
            const int kp = nt*2 + kph;
            #pragma unroll
            for (int r = 0; r < 4; ++r) {
                float t = acc[m][nt][r] * w_lds[ptb + r][cc];
                t += __shfl_xor(t, 1);
                t += __shfl_xor(t, 2);
                t += __shfl_xor(t, 4);
                if (cc == 0) pr_lds[ptb + r][kp] = t;
            }
        }
    }
    __syncthreads();

    // ---- Render scan (wave 0): 2 samples per lane ----
    if (wav == 0) {
        const float rnorm = sqrtf(ss);
        const int i0 = lane * 2;
        const float t0 = intr[ray*257 + i0];
        const float t1 = intr[ray*257 + i0 + 1];
        const float t2 = intr[ray*257 + i0 + 2];
        const float d0 = (t1 - t0) * rnorm;
        const float d1 = (t2 - t1) * rnorm;
        const float s0 = fmaxf(pr_lds[i0][3],     0.0f);
        const float s1 = fmaxf(pr_lds[i0 + 1][3], 0.0f);
        const float a0 = 1.0f - __expf(-s0 * d0);
        const float a1 = 1.0f - __expf(-s1 * d1);
        const float f0 = 1.0f - a0 + 1e-10f;
        const float f1 = 1.0f - a1 + 1e-10f;

        // inclusive product scan across 64 lanes
        float pprod = f0 * f1;
        #pragma unroll
        for (int off = 1; off < 64; off <<= 1) {
            float v = __shfl_up(pprod, off);
            if (lane >= off) pprod *= v;
        }
        float excl = __shfl_up(pprod, 1);
        if (lane == 0) excl = 1.0f;

        const float tr0 = excl;
        const float tr1 = excl * f0;
        const float al0 = a0 * tr0;
        const float al1 = a1 * tr1;
        const float mid0 = 0.5f * (t0 + t1);
        const float mid1 = 0.5f * (t1 + t2);

        const float r0 = 1.0f / (1.0f + __expf(-pr_lds[i0][0]));
        const float g0 = 1.0f / (1.0f + __expf(-pr_lds[i0][1]));
        const float b0 = 1.0f / (1.0f + __expf(-pr_lds[i0][2]));
        const float r1 = 1.0f / (1.0f + __expf(-pr_lds[i0 + 1][0]));
        const float g1 = 1.0f / (1.0f + __expf(-pr_lds[i0 + 1][1]));
        const float b1 = 1.0f / (1.0f + __expf(-pr_lds[i0 + 1][2]));

        float sum_r = al0*r0 + al1*r1;
        float sum_g = al0*g0 + al1*g1;
        float sum_b = al0*b0 + al1*b1;
        float sum_d = al0*mid0 + al1*mid1;
        float sum_a = al0 + al1;
        #pragma unroll
        for (int off = 1; off < 64; off <<= 1) {
            sum_r += __shfl_xor(sum_r, off);
            sum_g += __shfl_xor(sum_g, off);
            sum_b += __shfl_xor(sum_b, off);
            sum_d += __shfl_xor(sum_d, off);
            sum_a += __shfl_xor(sum_a, off);
        }
        if (lane == 0) {
            const float bkgd = 1.0f - sum_a;
            out_rgb[ray*3 + 0] = sum_r + bkgd;
            out_rgb[ray*3 + 1] = sum_g + bkgd;
            out_rgb[ray*3 + 2] = sum_b + bkgd;
            out_depth[ray]     = sum_d;
        }
        float2 av; av.x = a0; av.y = a1;
        *(float2*)(out_alpha + (size_t)ray*NINTRS + i0) = av;
        float2 zz; zz.x = 0.0f; zz.y = 0.0f;
        *(float2*)(out_alpha + (size_t)ray*NINTRS + VALID + i0) = zz;
    }
}

extern "C" void kernel_launch(void* const* d_in, const int* in_sizes, int n_in,
                              void* d_out, int out_size, void* d_ws, size_t ws_size,
                              hipStream_t stream)
{
    const float* q     = (const float*)d_in[0];
    const float* atoms = (const float*)d_in[1];
    const float* ipts  = (const float*)d_in[2];
    const float* intr  = (const float*)d_in[3];
    const float* raysd = (const float*)d_in[4];
    // d_in[5] (flat_idx) is b*NINTRS+i by construction; derived analytically.

    float* out = (float*)d_out;
    float* out_rgb   = out;                                  // 2048*3
    float* out_alpha = out + BATCH*3;                        // 2048*256
    float* out_depth = out + BATCH*3 + (size_t)BATCH*NINTRS; // 2048

    shdict_fused<<<BATCH, 256, 0, stream>>>(q, atoms, ipts, intr, raysd,
                                            out_rgb, out_alpha, out_depth);
}

// Round 3
// 90.742 us; speedup vs baseline: 1.5054x; 1.5054x over previous
//
#include <hip/hip_runtime.h>
#include <hip/hip_bf16.h>
#include <math.h>

#define BATCH   2048
#define NINTRS  256
#define VALID   128
#define NATOMS  256
#define DDIM    28   // 3*9+1

typedef float  f32x4  __attribute__((ext_vector_type(4)));
typedef short  bf16x8 __attribute__((ext_vector_type(8)));

__device__ __forceinline__ unsigned short f32_to_bf16(float f) {
    unsigned int u = __float_as_uint(f);
    u = (u + 0x7FFFu + ((u >> 16) & 1u)) >> 16;   // RNE
    return (unsigned short)u;
}

// One block per ray.  q is staged global->LDS via global_load_lds DMA,
// double-buffered in WAVE-PRIVATE slices: the K-loop has NO barriers,
// only counted s_waitcnt vmcnt(N) (T3/T4 pattern).  LDS q layout is
// XOR-swizzled (row&7 key, 128B rows) via pre-swizzled GLOBAL source
// (linear DMA dest + swizzled ds_read = rule #21).
__global__ __launch_bounds__(256)
void shdict_fused(const float* __restrict__ q,      // [BATCH*VALID][256]
                  const float* __restrict__ atoms,  // [256][28][8]
                  const float* __restrict__ ipts,   // [BATCH*VALID][3]
                  const float* __restrict__ intr,   // [BATCH][257]
                  const float* __restrict__ raysd,  // [BATCH][3]
                  float* __restrict__ out_rgb,      // [BATCH][3]
                  float* __restrict__ out_alpha,    // [BATCH][256]
                  float* __restrict__ out_depth)    // [BATCH]
{
    __shared__ char  bs[32 * 256 * 2];      // Bs[col][a] bf16, XOR-swizzled (16 KB)
    __shared__ float qbuf[2 * 128 * 32];    // q stage, 2 bufs (32 KB)
    __shared__ float w_lds[VALID][9];       // trilinear weights (+1 pad)
    __shared__ float pr_lds[VALID][5];      // rgb0,rgb1,rgb2,sigma (+1 pad)

    const int ray  = blockIdx.x;
    const int tid  = threadIdx.x;
    const int lane = tid & 63;
    const int wav  = tid >> 6;

    // ---- q staging addresses ----
    // Stage instr j of this wave covers local rows j*8..j*8+7 (128 B each).
    // Lane l writes LDS slot (row = j*8 + l/8, chunk = l&7); the data that
    // must land there is global 16B-chunk (l&7) ^ (row&7)  [row&7 == l/8].
    const int srow   = lane >> 3;                 // 0..7
    const int schunk = (lane & 7) ^ srow;         // inverse-swizzled chunk
    const char* gq = (const char*)q
        + ((size_t)(ray * VALID + wav * 32 + srow) << 10)   // row * 1024 B
        + ((size_t)schunk << 4);
    char* lqw = (char*)qbuf + (wav << 12);        // wave's 4 KB slice

    auto stage = [&](int ks, int bufi) {
        #pragma unroll
        for (int j = 0; j < 4; ++j) {
            __builtin_amdgcn_global_load_lds(
                (const __attribute__((address_space(1))) void*)(gq + ks * 128 + j * 8192),
                (__attribute__((address_space(3))) void*)(lqw + bufi * 16384 + j * 1024),
                16, 0, 0);
        }
    };

    // Prologue: issue ks=0,1 DMA now; they land under phase A/B compute
    // (the phase-B barrier drains vmcnt anyway).
    stage(0, 0);
    stage(1, 1);

    // ---- SH basis for this ray (redundant per thread) ----
    const float rdx = raysd[ray*3+0], rdy = raysd[ray*3+1], rdz = raysd[ray*3+2];
    const float ss  = rdx*rdx + rdy*rdy + rdz*rdz;
    const float rn  = rsqrtf(ss);
    const float x = rdx*rn, y = rdy*rn, z = rdz*rn;
    float sh[9];
    sh[0] = 0.28209479177387814f;
    sh[1] = -0.4886025119029199f * y;
    sh[2] =  0.4886025119029199f * z;
    sh[3] = -0.4886025119029199f * x;
    sh[4] =  1.0925484305920792f * x * y;
    sh[5] = -1.0925484305920792f * y * z;
    sh[6] =  0.31539156525252005f * (2.0f*z*z - x*x - y*y);
    sh[7] = -1.0925484305920792f * x * z;
    sh[8] =  0.5462742152960396f * (x*x - y*y);

    // ---- Phase A: trilinear weights for the 128 valid points ----
    if (tid < VALID) {
        const int n = ray * VALID + tid;
        const float px = ipts[n*3+0]*128.0f + 1e-5f;
        const float py = ipts[n*3+1]*128.0f + 1e-5f;
        const float pz = ipts[n*3+2]*128.0f + 1e-5f;
        const float fx = px - floorf(px);
        const float fy = py - floorf(py);
        const float fz = pz - floorf(pz);
        #pragma unroll
        for (int c = 0; c < 8; ++c) {
            const float wx = (c & 4) ? fx : 1.0f - fx;
            const float wy = (c & 2) ? fy : 1.0f - fy;
            const float wz = (c & 1) ? fz : 1.0f - fz;
            w_lds[tid][c] = wx * wy * wz;
        }
    }

    // ---- Phase B: Bs[col][a], a == tid.  col = kp*8+c; kp<3 are
    // sh-contracted rgb rows, col 24..31 is the raw sigma row (d=27). ----
    {
        const int a = tid;
        const float* __restrict__ arow = atoms + (size_t)a * (DDIM*8);
        float acc[3][8];
        #pragma unroll
        for (int k = 0; k < 3; ++k)
            #pragma unroll
            for (int c = 0; c < 8; ++c) acc[k][c] = 0.0f;
        #pragma unroll
        for (int d = 0; d < 27; ++d) {
            const int kp = d / 9, j = d - kp*9;
            const float s = sh[j];
            f32x4 a0 = *(const f32x4*)(arow + d*8);
            f32x4 a1 = *(const f32x4*)(arow + d*8 + 4);
            #pragma unroll
            for (int c = 0; c < 4; ++c) {
                acc[kp][c]   = fmaf(s, a0[c], acc[kp][c]);
                acc[kp][c+4] = fmaf(s, a1[c], acc[kp][c+4]);
            }
        }
        #pragma unroll
        for (int kp = 0; kp < 3; ++kp)
            #pragma unroll
            for (int c = 0; c < 8; ++c) {
                const int col = kp*8 + c;
                unsigned byte = ((unsigned)col << 9) + ((unsigned)a << 1);
                byte ^= (unsigned)((col & 7) << 4);
                *(unsigned short*)(bs + byte) = f32_to_bf16(acc[kp][c]);
            }
        f32x4 s0 = *(const f32x4*)(arow + 27*8);
        f32x4 s1 = *(const f32x4*)(arow + 27*8 + 4);
        #pragma unroll
        for (int c = 0; c < 8; ++c) {
            const int col = 24 + c;
            unsigned byte = ((unsigned)col << 9) + ((unsigned)a << 1);
            byte ^= (unsigned)((col & 7) << 4);
            *(unsigned short*)(bs + byte) = f32_to_bf16(c < 4 ? s0[c] : s1[c-4]);
        }
    }
    __syncthreads();   // bs ready; drains prologue DMA too

    // ---- Phase C: barrier-free K-loop, counted-vmcnt double buffer ----
    f32x4 acc[2][2];
    #pragma unroll
    for (int m = 0; m < 2; ++m)
        #pragma unroll
        for (int n = 0; n < 2; ++n)
            acc[m][n] = (f32x4){0.f, 0.f, 0.f, 0.f};

    const int row  = lane & 15;   // A row / B col within tile
    const int kgrp = lane >> 4;   // k sub-group of 8 within K=32
    const int key  = row & 7;     // read-side swizzle key (row&7 == (row+16)&7)

    #pragma unroll
    for (int ks = 0; ks < 8; ++ks) {
        // stage ks is complete once ≤4 (the ks+1 stage) remain outstanding
        if (ks < 7) asm volatile("s_waitcnt vmcnt(4)" ::: "memory");
        else        asm volatile("s_waitcnt vmcnt(0)" ::: "memory");

        const char* rb = (char*)qbuf + (ks & 1) * 16384 + (wav << 12);
        f32x4 a0l = *(const f32x4*)(rb + row*128        + (((2*kgrp+0) ^ key) << 4));
        f32x4 a0h = *(const f32x4*)(rb + row*128        + (((2*kgrp+1) ^ key) << 4));
        f32x4 a1l = *(const f32x4*)(rb + (row+16)*128   + (((2*kgrp+0) ^ key) << 4));
        f32x4 a1h = *(const f32x4*)(rb + (row+16)*128   + (((2*kgrp+1) ^ key) << 4));

        bf16x8 af[2];
        #pragma unroll
        for (int j = 0; j < 4; ++j) {
            af[0][j]   = (short)f32_to_bf16(a0l[j]);
            af[0][j+4] = (short)f32_to_bf16(a0h[j]);
            af[1][j]   = (short)f32_to_bf16(a1l[j]);
            af[1][j+4] = (short)f32_to_bf16(a1h[j]);
        }

        bf16x8 bfrag[2];
        const int abase = ks*32 + kgrp*8;
        #pragma unroll
        for (int nt = 0; nt < 2; ++nt) {
            const int col = nt*16 + row;
            unsigned byte = ((unsigned)col << 9) + ((unsigned)abase << 1);
            byte ^= (unsigned)((col & 7) << 4);
            bfrag[nt] = *(const bf16x8*)(bs + byte);
        }

        // refill the buffer we just consumed (wave-private slice; the
        // ds_reads above were issued first and complete ~700cy before
        // this DMA's data can return)
        if (ks + 2 < 8) stage(ks + 2, ks & 1);

        acc[0][0] = __builtin_amdgcn_mfma_f32_16x16x32_bf16(af[0], bfrag[0], acc[0][0], 0, 0, 0);
        acc[0][1] = __builtin_amdgcn_mfma_f32_16x16x32_bf16(af[0], bfrag[1], acc[0][1], 0, 0, 0);
        acc[1][0] = __builtin_amdgcn_mfma_f32_16x16x32_bf16(af[1], bfrag[0], acc[1][0], 0, 0, 0);
        acc[1][1] = __builtin_amdgcn_mfma_f32_16x16x32_bf16(af[1], bfrag[1], acc[1][1], 0, 0, 0);
    }

    // ---- Epilogue: out[pt,kp] = sum_c w[pt,c] * C[pt, kp*8+c] ----
    // D layout: lane holds D[(lane>>4)*4 + r][lane&15].
    const int cc  = lane & 7;
    const int kph = (lane & 15) >> 3;
    #pragma unroll
    for (int m = 0; m < 2; ++m) {
        const int ptb = wav*32 + m*16 + kgrp*4;
        #pragma unroll
        for (int nt = 0; nt < 2; ++nt) {
            const int kp = nt*2 + kph;
            #pragma unroll
            for (int r = 0; r < 4; ++r) {
                float t = acc[m][nt][r] * w_lds[ptb + r][cc];
                t += __shfl_xor(t, 1);
                t += __shfl_xor(t, 2);
                t += __shfl_xor(t, 4);
                if (cc == 0) pr_lds[ptb + r][kp] = t;
            }
        }
    }
    __syncthreads();

    // ---- Render scan (wave 0): 2 samples per lane ----
    if (wav == 0) {
        const float rnorm = sqrtf(ss);
        const int i0 = lane * 2;
        const float t0 = intr[ray*257 + i0];
        const float t1 = intr[ray*257 + i0 + 1];
        const float t2 = intr[ray*257 + i0 + 2];
        const float d0 = (t1 - t0) * rnorm;
        const float d1 = (t2 - t1) * rnorm;
        const float s0 = fmaxf(pr_lds[i0][3],     0.0f);
        const float s1 = fmaxf(pr_lds[i0 + 1][3], 0.0f);
        const float a0 = 1.0f - __expf(-s0 * d0);
        const float a1 = 1.0f - __expf(-s1 * d1);
        const float f0 = 1.0f - a0 + 1e-10f;
        const float f1 = 1.0f - a1 + 1e-10f;

        // inclusive product scan across 64 lanes
        float pprod = f0 * f1;
        #pragma unroll
        for (int off = 1; off < 64; off <<= 1) {
            float v = __shfl_up(pprod, off);
            if (lane >= off) pprod *= v;
        }
        float excl = __shfl_up(pprod, 1);
        if (lane == 0) excl = 1.0f;

        const float tr0 = excl;
        const float tr1 = excl * f0;
        const float al0 = a0 * tr0;
        const float al1 = a1 * tr1;
        const float mid0 = 0.5f * (t0 + t1);
        const float mid1 = 0.5f * (t1 + t2);

        const float r0 = 1.0f / (1.0f + __expf(-pr_lds[i0][0]));
        const float g0 = 1.0f / (1.0f + __expf(-pr_lds[i0][1]));
        const float b0 = 1.0f / (1.0f + __expf(-pr_lds[i0][2]));
        const float r1 = 1.0f / (1.0f + __expf(-pr_lds[i0 + 1][0]));
        const float g1 = 1.0f / (1.0f + __expf(-pr_lds[i0 + 1][1]));
        const float b1 = 1.0f / (1.0f + __expf(-pr_lds[i0 + 1][2]));

        float sum_r = al0*r0 + al1*r1;
        float sum_g = al0*g0 + al1*g1;
        float sum_b = al0*b0 + al1*b1;
        float sum_d = al0*mid0 + al1*mid1;
        float sum_a = al0 + al1;
        #pragma unroll
        for (int off = 1; off < 64; off <<= 1) {
            sum_r += __shfl_xor(sum_r, off);
            sum_g += __shfl_xor(sum_g, off);
            sum_b += __shfl_xor(sum_b, off);
            sum_d += __shfl_xor(sum_d, off);
            sum_a += __shfl_xor(sum_a, off);
        }
        if (lane == 0) {
            const float bkgd = 1.0f - sum_a;
            out_rgb[ray*3 + 0] = sum_r + bkgd;
            out_rgb[ray*3 + 1] = sum_g + bkgd;
            out_rgb[ray*3 + 2] = sum_b + bkgd;
            out_depth[ray]     = sum_d;
        }
        float2 av; av.x = a0; av.y = a1;
        *(float2*)(out_alpha + (size_t)ray*NINTRS + i0) = av;
        float2 zz; zz.x = 0.0f; zz.y = 0.0f;
        *(float2*)(out_alpha + (size_t)ray*NINTRS + VALID + i0) = zz;
    }
}

extern "C" void kernel_launch(void* const* d_in, const int* in_sizes, int n_in,
                              void* d_out, int out_size, void* d_ws, size_t ws_size,
                              hipStream_t stream)
{
    const float* q     = (const float*)d_in[0];
    const float* atoms = (const float*)d_in[1];
    const float* ipts  = (const float*)d_in[2];
    const float* intr  = (const float*)d_in[3];
    const float* raysd = (const float*)d_in[4];
    // d_in[5] (flat_idx) is b*NINTRS+i by construction; derived analytically.

    float* out = (float*)d_out;
    float* out_rgb   = out;                                  // 2048*3
    float* out_alpha = out + BATCH*3;                        // 2048*256
    float* out_depth = out + BATCH*3 + (size_t)BATCH*NINTRS; // 2048

    shdict_fused<<<BATCH, 256, 0, stream>>>(q, atoms, ipts, intr, raysd,
                                            out_rgb, out_alpha, out_depth);
}